// Round 14
// baseline (101.690 us; speedup 1.0000x reference)
//
#include <hip/hip_runtime.h>

#define BATCH 4
#define SEQ   2048
#define EMB   128
#define NH    16
#define DK    8

// log2(e) / sqrt(8): fold softmax temperature into exp2 (pre-multiplied into qf)
#define QSCALE 0.510069726f

typedef _Float16 v2h __attribute__((ext_vector_type(2)));
typedef _Float16 v4h __attribute__((ext_vector_type(4)));
typedef __fp16   v2fp __attribute__((ext_vector_type(2)));
typedef float    v4f __attribute__((ext_vector_type(4)));

#define CHUNK  256          // keys per LDS stage
#define NCH    4            // chunks per split (split covers 1024 keys)
#define VTPAD  264          // VT row pitch (f16): breaks pow2 stride
#define NROW   (BATCH * SEQ)        // 8192 embedding rows
#define NHROW  (BATCH * NH * SEQ)   // 131072 head-rows
#define PSTR   12           // partial row stride (floats): 8 acc + den, 16B-aligned

// ---------------------------------------------------------------------------
// Fused features + MFMA attention, SPLIT-K over keys.
// Grid = 64 bh x 16 qchunk x 2 ksplit = 2048 blocks; block = 256 thr = 4
// waves; wave owns 32 q (2 16-row tiles, t=2). LDS 12.3 KB -> 8 blocks/CU
// = 32 waves/CU = 8 waves/SIMD — first config with BOTH t=2 ILP and full
// wave occupancy (R8-R13 all had one or the other; all plateaued at 42 us).
//
// Each split stages its own 4 chunks (1024 keys); q-frags are SELF-COMPUTED
// from x (q may lie outside the split's key range). Blocks write
// unnormalized f32 partials (8 acc + den per head-row); reduce_kernel
// combines the 2 splits and normalizes. Plain-exp softmax is exact
// (|score*log2e/sqrt8| <= 4.1) and split combination is sum-order only.
//
// Per 16-key tile: S^T = mfma_16x16x16_f16(A=K, B=Q^T). C-layout {q=L&15,
// key=quad*4+r} == B-frag layout {n=L&15, k=quad*4+j}, so P = exp2(S^T)
// feeds out^T = mfma(A=V^T, B=P^T, acc) in registers (pkrtz pack). qf is 0
// in quads 2-3 so padded-K garbage multiplies by zero. Ones-row d=8 of V^T
// accumulates the denominator.
// ---------------------------------------------------------------------------
__launch_bounds__(256, 8)
__global__ void attn_kernel(const float* __restrict__ x,
                            const float* __restrict__ theta,
                            float* __restrict__ Pp /* [2][NHROW][PSTR] f32 */) {
  __shared__ __align__(16) _Float16 Kl[CHUNK * 8];   // 4 KB
  __shared__ __align__(16) _Float16 VT[16][VTPAD];   // 8.25 KB

  const int tid  = threadIdx.x;
  const int L    = tid & 63;
  const int quad = L >> 4;
  const int ln   = L & 15;
  const int wv   = tid >> 6;                  // wave 0..3
  const int bh     = blockIdx.x >> 5;         // 64
  const int qchunk = (blockIdx.x >> 1) & 15;  // 16
  const int split  = blockIdx.x & 1;          // 2
  const int qb     = qchunk * 128 + wv * 32;  // wave's 32 q rows
  const int b = bh >> 4;
  const int h = bh & 15;

  float th[DK];
#pragma unroll
  for (int i = 0; i < DK; ++i) th[i] = theta[i];

  // VT rows 8-15: row 8 = ones (denominator), rows 9-15 = 0
  for (int i = tid; i < 8 * VTPAD / 4; i += 256) {
    v4h v = (i < VTPAD / 4) ? (v4h){(_Float16)1.f, (_Float16)1.f,
                                    (_Float16)1.f, (_Float16)1.f}
                            : (v4h){0, 0, 0, 0};
    *(v4h*)(&VT[8][0] + i * 4) = v;
  }

  // ---- self-compute q fragments (q rows may be outside this split) ----
  v4h qf[2] = {{0, 0, 0, 0}, {0, 0, 0, 0}};
  if (quad < 2) {
#pragma unroll
    for (int t = 0; t < 2; ++t) {
      const int qrow = qb + t * 16 + ln;
      const float* xq = x + ((size_t)b * SEQ + qrow) * EMB + h * DK;
      const float4 a0 = *(const float4*)(xq);
      const float4 a1 = *(const float4*)(xq + 4);
      float r[8];
      r[0] = __cosf(a0.x + th[0]);
      r[1] = r[0] * __cosf(a0.y + th[1]);
      r[2] = r[1] * __cosf(a0.z + th[2]);
      r[3] = r[2] * __cosf(a0.w + th[3]);
      r[4] = r[3] * __cosf(a1.x + th[4]);
      r[5] = r[4] * __cosf(a1.y + th[5]);
      r[6] = r[5] * __cosf(a1.z + th[6]);
      r[7] = r[6] * __cosf(a1.w + th[7]);
      qf[t] = (v4h){(_Float16)(r[quad * 4 + 0] * QSCALE),
                    (_Float16)(r[quad * 4 + 1] * QSCALE),
                    (_Float16)(r[quad * 4 + 2] * QSCALE),
                    (_Float16)(r[quad * 4 + 3] * QSCALE)};
    }
  }

  const float* xb = x + (size_t)b * SEQ * EMB + h * DK;
  const int cbase = split * NCH;
  float4 pa0, pa1;
  {
    const float* xp = xb + (size_t)(cbase * CHUNK + tid) * EMB;
    pa0 = *(const float4*)(xp);
    pa1 = *(const float4*)(xp + 4);
  }

  v4f acc[2];
  acc[0] = (v4f){0.f, 0.f, 0.f, 0.f};
  acc[1] = (v4f){0.f, 0.f, 0.f, 0.f};
  const v4f zf = (v4f){0.f, 0.f, 0.f, 0.f};

  for (int cc = 0; cc < NCH; ++cc) {
    // ---- stage chunk (1 key/thread: Kl b128 16 B/lane, VT b16 — R10's
    //      measured-conflict-free pattern) ----
    {
      float r[8];
      r[0] = __cosf(pa0.x + th[0]);
      r[1] = r[0] * __cosf(pa0.y + th[1]);
      r[2] = r[1] * __cosf(pa0.z + th[2]);
      r[3] = r[2] * __cosf(pa0.w + th[3]);
      r[4] = r[3] * __cosf(pa1.x + th[4]);
      r[5] = r[4] * __cosf(pa1.y + th[5]);
      r[6] = r[5] * __cosf(pa1.z + th[6]);
      r[7] = r[6] * __cosf(pa1.w + th[7]);
      _Float16 hv[8];
#pragma unroll
      for (int i = 0; i < 8; ++i) hv[i] = (_Float16)r[i];
      union { v4h v[2]; float4 f; } u;
      u.v[0] = (v4h){hv[0], hv[1], hv[2], hv[3]};
      u.v[1] = (v4h){hv[4], hv[5], hv[6], hv[7]};
      *(float4*)&Kl[tid * 8] = u.f;
#pragma unroll
      for (int d = 0; d < 8; ++d) VT[d][tid] = hv[d];
    }
    __syncthreads();

    // prefetch next chunk's x row (overlaps compute)
    if (cc + 1 < NCH) {
      const float* xp = xb + (size_t)((cbase + cc + 1) * CHUNK + tid) * EMB;
      pa0 = *(const float4*)(xp);
      pa1 = *(const float4*)(xp + 4);
    }

    // ---- compute: 16 16-key tiles, 2 q-tiles each ----
    for (int t16 = 0; t16 < CHUNK / 16; ++t16) {
      const v4h kf = *(const v4h*)&Kl[(t16 * 16 + ln) * 8 + (quad & 1) * 4];
      const v4h vt = *(const v4h*)&VT[ln][t16 * 16 + quad * 4];
#pragma unroll
      for (int t = 0; t < 2; ++t) {
        const v4f s = __builtin_amdgcn_mfma_f32_16x16x16f16(kf, qf[t], zf, 0, 0, 0);
        union { v2fp p[2]; v4h v; } pk;
        pk.p[0] = __builtin_amdgcn_cvt_pkrtz(__builtin_amdgcn_exp2f(s[0]),
                                             __builtin_amdgcn_exp2f(s[1]));
        pk.p[1] = __builtin_amdgcn_cvt_pkrtz(__builtin_amdgcn_exp2f(s[2]),
                                             __builtin_amdgcn_exp2f(s[3]));
        acc[t] = __builtin_amdgcn_mfma_f32_16x16x16f16(vt, pk.v, acc[t], 0, 0, 0);
      }
    }
    __syncthreads();
  }

  // ---- epilogue: store unnormalized partials ----
  // acc[t] = out^T[d=quad*4+r][q=ln]; den row d=8 lives at quad==2, reg 0.
  float* pb = Pp + ((size_t)split * NHROW + (size_t)bh * SEQ) * PSTR;
#pragma unroll
  for (int t = 0; t < 2; ++t) {
    const int qrow = qb + t * 16 + ln;
    if (quad < 2) {
      float4 st = make_float4(acc[t][0], acc[t][1], acc[t][2], acc[t][3]);
      *(float4*)(pb + (size_t)qrow * PSTR + quad * 4) = st;
    } else if (quad == 2) {
      pb[(size_t)qrow * PSTR + 8] = acc[t][0];
    }
  }
}

// ---------------------------------------------------------------------------
// Combine splits + normalize -> Ah f16. Thread = one (row, head); 16
// consecutive threads cover one embedding row -> coalesced 256 B stores.
// ---------------------------------------------------------------------------
__global__ void reduce_kernel(const float* __restrict__ Pp,
                              _Float16* __restrict__ Ah) {
  const int gid = blockIdx.x * 256 + threadIdx.x;   // 131072
  const int row = gid >> 4;        // b*SEQ + s  (0..8191)
  const int h   = gid & 15;
  const int b   = row >> 11;
  const int s   = row & (SEQ - 1);
  const size_t pidx = ((size_t)(b * NH + h) * SEQ + s) * PSTR;

  const float* p0 = Pp + pidx;
  const float* p1 = Pp + (size_t)NHROW * PSTR + pidx;
  const float4 a0 = *(const float4*)(p0);
  const float4 a1 = *(const float4*)(p0 + 4);
  const float4 b0 = *(const float4*)(p1);
  const float4 b1 = *(const float4*)(p1 + 4);
  const float inv = 1.0f / (p0[8] + p1[8]);

  union { v4h v[2]; float4 f; } o;
  o.v[0] = (v4h){(_Float16)((a0.x + b0.x) * inv), (_Float16)((a0.y + b0.y) * inv),
                 (_Float16)((a0.z + b0.z) * inv), (_Float16)((a0.w + b0.w) * inv)};
  o.v[1] = (v4h){(_Float16)((a1.x + b1.x) * inv), (_Float16)((a1.y + b1.y) * inv),
                 (_Float16)((a1.z + b1.z) * inv), (_Float16)((a1.w + b1.w) * inv)};
  *(float4*)(Ah + (size_t)row * EMB + h * DK) = o.f;
}

// ---------------------------------------------------------------------------
// MFMA projection (unchanged). out = Ah · W^T, fp32 out. W f32->f16 during
// LDS staging; W row-major IS the B-fragment source. Block: 64 rows x 64
// cols (grid 128x2), LDS 35 KB, 4 blocks/CU.
// ---------------------------------------------------------------------------
__launch_bounds__(256, 4)
__global__ void proj_kernel(const _Float16* __restrict__ Ah,
                            const float* __restrict__ W,
                            float* __restrict__ out) {
  __shared__ __align__(16) _Float16 Ahs[64][136];
  __shared__ __align__(16) _Float16 Whs[64][136];

  const int tid  = threadIdx.x;
  const int L    = tid & 63;
  const int wv   = tid >> 6;
  const int quad = L >> 4;
  const int ln   = L & 15;
  const int rowbase = blockIdx.x * 64;
  const int colbase = blockIdx.y * 64;

#pragma unroll
  for (int it = 0; it < 4; ++it) {
    const int idx = it * 256 + tid;
    const int r  = idx >> 4;
    const int c8 = idx & 15;
    *(uint4*)&Ahs[r][c8 * 8] =
        *(const uint4*)(Ah + (size_t)(rowbase + r) * EMB + c8 * 8);
  }
#pragma unroll
  for (int it = 0; it < 8; ++it) {
    const int idx = it * 256 + tid;
    const int n  = idx >> 5;
    const int c4 = idx & 31;
    const float4 w = *(const float4*)(W + (size_t)(colbase + n) * EMB + c4 * 4);
    v4h wh = {(_Float16)w.x, (_Float16)w.y, (_Float16)w.z, (_Float16)w.w};
    *(v4h*)&Whs[n][c4 * 4] = wh;
  }
  __syncthreads();

  v4f acc[4];
#pragma unroll
  for (int nt = 0; nt < 4; ++nt) acc[nt] = (v4f){0.f, 0.f, 0.f, 0.f};

#pragma unroll
  for (int k8 = 0; k8 < 8; ++k8) {
    const v4h af = *(const v4h*)&Ahs[wv * 16 + ln][k8 * 16 + quad * 4];
#pragma unroll
    for (int nt = 0; nt < 4; ++nt) {
      const v4h bf = *(const v4h*)&Whs[nt * 16 + ln][k8 * 16 + quad * 4];
      acc[nt] = __builtin_amdgcn_mfma_f32_16x16x16f16(af, bf, acc[nt], 0, 0, 0);
    }
  }

#pragma unroll
  for (int nt = 0; nt < 4; ++nt) {
    const int col = colbase + nt * 16 + ln;
#pragma unroll
    for (int r = 0; r < 4; ++r) {
      out[(size_t)(rowbase + wv * 16 + quad * 4 + r) * EMB + col] = acc[nt][r];
    }
  }
}

// ---------------------------------------------------------------------------
extern "C" void kernel_launch(void* const* d_in, const int* in_sizes, int n_in,
                              void* d_out, int out_size, void* d_ws, size_t ws_size,
                              hipStream_t stream) {
  const float* x     = (const float*)d_in[0];  // [4,2048,128]
  const float* theta = (const float*)d_in[1];  // [8]
  const float* w_out = (const float*)d_in[2];  // [128,128]
  float* out = (float*)d_out;                  // [4,2048,128]

  _Float16* Ah = (_Float16*)d_ws;                             // 2 MB
  float*    Pp = (float*)((char*)d_ws + (size_t)4 * 1024 * 1024);  // 12.6 MB

  // split-K attention: 64 bh x 16 qchunk x 2 splits = 2048 blocks
  attn_kernel<<<dim3(2048), dim3(256), 0, stream>>>(x, theta, Pp);

  // combine + normalize: 131072 head-rows
  reduce_kernel<<<dim3(512), dim3(256), 0, stream>>>(Pp, Ah);

  // projection: 128 row-tiles x 2 col-tiles
  proj_kernel<<<dim3(NROW / 64, 2), dim3(256), 0, stream>>>(Ah, w_out, out);
}

// Round 15
// 94.728 us; speedup vs baseline: 1.0735x; 1.0735x over previous
//
#include <hip/hip_runtime.h>

#define BATCH 4
#define SEQ   2048
#define EMB   128
#define NH    16
#define DK    8

// log2(e) / sqrt(8): fold softmax temperature into exp2 (pre-multiplied into qf)
#define QSCALE 0.510069726f

typedef _Float16 v4h  __attribute__((ext_vector_type(4)));
typedef _Float16 v8h  __attribute__((ext_vector_type(8)));
typedef __fp16   v2fp __attribute__((ext_vector_type(2)));
typedef float    v4f  __attribute__((ext_vector_type(4)));
typedef float    v16f __attribute__((ext_vector_type(16)));

#define CHUNK  512
#define NCH    (SEQ / CHUNK)   // 4
#define VTP    520             // VT col pitch (f16): 260 dwords %32 = 4 -> 2-way max

// ---------------------------------------------------------------------------
// Fused features + 32x32 MFMA attention.
// Block = 256 thr = 4 waves; wave owns 32 q-rows; block covers 128 q.
// Grid = 64 bh x 16 = 1024 blocks. LDS ~18.5 KB.
//
// Per 32-key block (per wave):  S^T = mfma_f32_32x32x16_f16(A=K, B=Q^T)
//   A: lane m=L&31 holds key m's 8 dims (k-slots (L>>5)*8+j); half1's k=8..15
//      slots are killed by qf=0 on half1 (garbage * 0).
//   C/D layout (HW-verified m74/m101): col=i=L&31, row=j=(reg&3)+8(reg>>2)+4(L>>5).
// P = exp2(S^T) -> 16 INDEPENDENT exps per mfma (vs 4 in the 16x16 scheme:
// the mfma->exp dependency chain amortizes 4x better). Pack: B-frag for
//   out^T += mfma(A=V^T, B=P) is EXACTLY pkrtz(s[2i],s[2i+1]) in natural reg
// order for BOTH lane halves, PROVIDED V^T is stored with the within-16 key
// index bits 2<->3 swapped (mfma k-slots may be consistently permuted in A
// and B). No cross-lane exchange, no selects.
// Ones-row d=8 of V^T accumulates the softmax denominator; out rows 9..31
// are garbage (A reads clamped VT row 9) and are never stored.
// Plain-exp softmax is exact: |score*log2e/sqrt8| <= 4.1 (features <= 1).
// ---------------------------------------------------------------------------
__launch_bounds__(256, 4)
__global__ void attn_kernel(const float* __restrict__ x,
                            const float* __restrict__ theta,
                            _Float16* __restrict__ Ah /* [B*S][128] f16 */) {
  __shared__ __align__(16) _Float16 Kl[CHUNK * 8];   // 8 KB: [key][8 dims]
  __shared__ __align__(16) _Float16 VT[10][VTP];     // 10.2 KB: d 0-7, 8=ones, 9=junk

  const int tid = threadIdx.x;
  const int L   = tid & 63;
  const int ln  = L & 31;
  const int hf  = L >> 5;           // lane half
  const int wv  = tid >> 6;         // wave 0..3
  const int bh     = blockIdx.x >> 4;
  const int qchunk = blockIdx.x & 15;
  const int qb     = qchunk * 128 + wv * 32;   // wave's 32 q rows
  const int b = bh >> 4;
  const int h = bh & 15;

  float th[DK];
#pragma unroll
  for (int i = 0; i < DK; ++i) th[i] = theta[i];

  // VT row 8 = ones (denominator; persists across restages), row 9 = 0 (clamp target)
  for (int i = tid; i < VTP; i += 256) {
    VT[8][i] = (_Float16)1.0f;
    VT[9][i] = (_Float16)0.0f;
  }

  const int c0 = qchunk >> 2;       // 512-chunk containing this block's q rows
  const int mrow = (ln < 9) ? ln : 9;   // clamped VT row for PV A-frag
  const float* xb = x + (size_t)b * SEQ * EMB + h * DK;

  float4 pa0, pa1, pb0, pb1;        // prefetched x rows (keys tid, tid+256)
  {
    const float* xp = xb + (size_t)(c0 * CHUNK + tid) * EMB;
    pa0 = *(const float4*)(xp);
    pa1 = *(const float4*)(xp + 4);
    pb0 = *(const float4*)(xp + 256 * EMB);
    pb1 = *(const float4*)(xp + 256 * EMB + 4);
  }

  v8h qf = {0, 0, 0, 0, 0, 0, 0, 0};
  v16f acc;
#pragma unroll
  for (int i = 0; i < 16; ++i) acc[i] = 0.f;
  v16f zf;
#pragma unroll
  for (int i = 0; i < 16; ++i) zf[i] = 0.f;

  for (int cc = 0; cc < NCH; ++cc) {
    if (cc) __syncthreads();

    // ---- stage: features for keys tid, tid+256 (16 B/lane Kl writes) ----
    {
      float r0[8], r1[8];
      r0[0] = __cosf(pa0.x + th[0]);
      r0[1] = r0[0] * __cosf(pa0.y + th[1]);
      r0[2] = r0[1] * __cosf(pa0.z + th[2]);
      r0[3] = r0[2] * __cosf(pa0.w + th[3]);
      r0[4] = r0[3] * __cosf(pa1.x + th[4]);
      r0[5] = r0[4] * __cosf(pa1.y + th[5]);
      r0[6] = r0[5] * __cosf(pa1.z + th[6]);
      r0[7] = r0[6] * __cosf(pa1.w + th[7]);
      r1[0] = __cosf(pb0.x + th[0]);
      r1[1] = r1[0] * __cosf(pb0.y + th[1]);
      r1[2] = r1[1] * __cosf(pb0.z + th[2]);
      r1[3] = r1[2] * __cosf(pb0.w + th[3]);
      r1[4] = r1[3] * __cosf(pb1.x + th[4]);
      r1[5] = r1[4] * __cosf(pb1.y + th[5]);
      r1[6] = r1[5] * __cosf(pb1.z + th[6]);
      r1[7] = r1[6] * __cosf(pb1.w + th[7]);

      _Float16 h0[8], h1[8];
#pragma unroll
      for (int i = 0; i < 8; ++i) { h0[i] = (_Float16)r0[i]; h1[i] = (_Float16)r1[i]; }

      union { v4h v[2]; float4 f; } u0, u1;
      u0.v[0] = (v4h){h0[0], h0[1], h0[2], h0[3]};
      u0.v[1] = (v4h){h0[4], h0[5], h0[6], h0[7]};
      u1.v[0] = (v4h){h1[0], h1[1], h1[2], h1[3]};
      u1.v[1] = (v4h){h1[4], h1[5], h1[6], h1[7]};
      *(float4*)&Kl[tid * 8]         = u0.f;
      *(float4*)&Kl[(tid + 256) * 8] = u1.f;

      // VT with within-16 slot perm (swap bits 2<->3 of key index)
      const int j0 = tid, j1 = tid + 256;
      const int col0 = (j0 & ~15) | (j0 & 3) | ((j0 & 4) << 1) | ((j0 & 8) >> 1);
      const int col1 = (j1 & ~15) | (j1 & 3) | ((j1 & 4) << 1) | ((j1 & 8) >> 1);
#pragma unroll
      for (int d = 0; d < 8; ++d) {
        VT[d][col0] = h0[d];
        VT[d][col1] = h1[d];
      }
    }
    __syncthreads();

    // prefetch next chunk's x rows (consumed after the compute phase)
    if (cc + 1 < NCH) {
      const int cn = (c0 + cc + 1) & (NCH - 1);
      const float* xp = xb + (size_t)(cn * CHUNK + tid) * EMB;
      pa0 = *(const float4*)(xp);
      pa1 = *(const float4*)(xp + 4);
      pb0 = *(const float4*)(xp + 256 * EMB);
      pb1 = *(const float4*)(xp + 256 * EMB + 4);
    }

    // qf from Kl on the q-containing chunk (visited first); half1 stays 0
    if (cc == 0 && hf == 0) {
      const int ql = (qchunk & 3) * 128 + wv * 32 + ln;
      v8h qv = *(const v8h*)&Kl[ql * 8];
      const _Float16 qs = (_Float16)QSCALE;
      const v8h qsc = {qs, qs, qs, qs, qs, qs, qs, qs};
      qf = qv * qsc;
    }

    // ---- compute: 16 32-key blocks ----
    for (int kb = 0; kb < CHUNK / 32; ++kb) {
      const v8h kf = *(const v8h*)&Kl[(kb * 32 + ln) * 8];
      const v16f s = __builtin_amdgcn_mfma_f32_32x32x16_f16(kf, qf, zf, 0, 0, 0);
      union { v2fp p[4]; v8h v; } p0, p1;
#pragma unroll
      for (int i = 0; i < 4; ++i) {
        p0.p[i] = __builtin_amdgcn_cvt_pkrtz(
            __builtin_amdgcn_exp2f(s[2 * i]),
            __builtin_amdgcn_exp2f(s[2 * i + 1]));
        p1.p[i] = __builtin_amdgcn_cvt_pkrtz(
            __builtin_amdgcn_exp2f(s[8 + 2 * i]),
            __builtin_amdgcn_exp2f(s[8 + 2 * i + 1]));
      }
      const v8h vt0 = *(const v8h*)&VT[mrow][kb * 32 + hf * 8];
      const v8h vt1 = *(const v8h*)&VT[mrow][kb * 32 + 16 + hf * 8];
      acc = __builtin_amdgcn_mfma_f32_32x32x16_f16(vt0, p0.v, acc, 0, 0, 0);
      acc = __builtin_amdgcn_mfma_f32_32x32x16_f16(vt1, p1.v, acc, 0, 0, 0);
    }
  }

  // ---- epilogue ----
  // acc C-layout: col=q=L&31, row=(reg&3)+8(reg>>2)+4*hf.
  // half0 regs 0-3 = dims 0-3, reg4 = row 8 = den; half1 regs 0-3 = dims 4-7.
  {
    const float den = __shfl(acc[4], ln, 64);   // from half0 lane ln
    const float inv = 1.0f / den;
    const int qrow = qb + ln;
    v4h o = {(_Float16)(acc[0] * inv), (_Float16)(acc[1] * inv),
             (_Float16)(acc[2] * inv), (_Float16)(acc[3] * inv)};
    *(v4h*)(Ah + ((size_t)b * SEQ + qrow) * EMB + h * DK + hf * 4) = o;
  }
}

// ---------------------------------------------------------------------------
// MFMA projection (unchanged from R10-R13). out = Ah · W^T, fp32 out.
// W converted f32->f16 during LDS staging; W row-major IS the B-fragment
// source. Block: 64 rows x 64 cols (grid 128x2), LDS 35 KB, 4 blocks/CU.
// ---------------------------------------------------------------------------
__launch_bounds__(256, 4)
__global__ void proj_kernel(const _Float16* __restrict__ Ah,
                            const float* __restrict__ W,
                            float* __restrict__ out) {
  __shared__ __align__(16) _Float16 Ahs[64][136];
  __shared__ __align__(16) _Float16 Whs[64][136];

  const int tid  = threadIdx.x;
  const int L    = tid & 63;
  const int wv   = tid >> 6;
  const int quad = L >> 4;
  const int ln   = L & 15;
  const int rowbase = blockIdx.x * 64;
  const int colbase = blockIdx.y * 64;

#pragma unroll
  for (int it = 0; it < 4; ++it) {
    const int idx = it * 256 + tid;
    const int r  = idx >> 4;
    const int c8 = idx & 15;
    *(uint4*)&Ahs[r][c8 * 8] =
        *(const uint4*)(Ah + (size_t)(rowbase + r) * EMB + c8 * 8);
  }
#pragma unroll
  for (int it = 0; it < 8; ++it) {
    const int idx = it * 256 + tid;
    const int n  = idx >> 5;
    const int c4 = idx & 31;
    const float4 w = *(const float4*)(W + (size_t)(colbase + n) * EMB + c4 * 4);
    v4h wh = {(_Float16)w.x, (_Float16)w.y, (_Float16)w.z, (_Float16)w.w};
    *(v4h*)&Whs[n][c4 * 4] = wh;
  }
  __syncthreads();

  v4f acc[4];
#pragma unroll
  for (int nt = 0; nt < 4; ++nt) acc[nt] = (v4f){0.f, 0.f, 0.f, 0.f};

#pragma unroll
  for (int k8 = 0; k8 < 8; ++k8) {
    const v4h af = *(const v4h*)&Ahs[wv * 16 + ln][k8 * 16 + quad * 4];
#pragma unroll
    for (int nt = 0; nt < 4; ++nt) {
      const v4h bf = *(const v4h*)&Whs[nt * 16 + ln][k8 * 16 + quad * 4];
      acc[nt] = __builtin_amdgcn_mfma_f32_16x16x16f16(af, bf, acc[nt], 0, 0, 0);
    }
  }

#pragma unroll
  for (int nt = 0; nt < 4; ++nt) {
    const int col = colbase + nt * 16 + ln;
#pragma unroll
    for (int r = 0; r < 4; ++r) {
      out[(size_t)(rowbase + wv * 16 + quad * 4 + r) * EMB + col] = acc[nt][r];
    }
  }
}

// ---------------------------------------------------------------------------
extern "C" void kernel_launch(void* const* d_in, const int* in_sizes, int n_in,
                              void* d_out, int out_size, void* d_ws, size_t ws_size,
                              hipStream_t stream) {
  const float* x     = (const float*)d_in[0];  // [4,2048,128]
  const float* theta = (const float*)d_in[1];  // [8]
  const float* w_out = (const float*)d_in[2];  // [128,128]
  float* out = (float*)d_out;                  // [4,2048,128]

  _Float16* Ah = (_Float16*)d_ws;              // [8192][128] f16 = 2 MB

  // fused features + attention: 64 bh x 16 q-chunks = 1024 blocks, 4 waves
  attn_kernel<<<dim3(1024), dim3(256), 0, stream>>>(x, theta, Ah);

  // projection: 128 row-tiles x 2 col-tiles
  proj_kernel<<<dim3((BATCH * SEQ) / 64, 2), dim3(256), 0, stream>>>(Ah, w_out, out);
}

// Round 16
// 93.788 us; speedup vs baseline: 1.0843x; 1.0100x over previous
//
#include <hip/hip_runtime.h>

#define BATCH 4
#define SEQ   2048
#define EMB   128
#define NH    16
#define DK    8

// log2(e) / sqrt(8): fold softmax temperature into exp2 (pre-multiplied into qf)
#define QSCALE 0.510069726f

typedef _Float16 v4h  __attribute__((ext_vector_type(4)));
typedef _Float16 v8h  __attribute__((ext_vector_type(8)));
typedef __fp16   v2fp __attribute__((ext_vector_type(2)));
typedef float    v4f  __attribute__((ext_vector_type(4)));
typedef float    v16f __attribute__((ext_vector_type(16)));

#define CHUNK  512
#define NCH    (SEQ / CHUNK)   // 4
#define VTP    520             // VT col pitch (f16): 260 dwords %32 = 4 -> 2-way max

// ---------------------------------------------------------------------------
// Fused features + 32x32 MFMA attention (R15 structure + software pipeline).
// Block = 256 thr = 4 waves; wave owns 32 q-rows; block covers 128 q.
// Grid = 64 bh x 16 = 1024 blocks. LDS ~18.5 KB, 4 blocks/CU.
//
// Issue-port model (R13 counters): trans (exp@8cyc) + VALU ≈ 25 us of
// unhideable SIMD issue time; the rest of the measured ~40 us is LDS-latency
// holes in the kf->mfma->exp->pack->mfma chain. This round pipelines:
// kf prefetched one kb ahead, vt prefetched before the exp block, and the
// kb loop unrolled 2x for two independent chains in flight.
//
// Math (HW-verified layouts): S^T = mfma_32x32x16(A=K, B=Q^T); C/D layout
// col=L&31, row=(reg&3)+8(reg>>2)+4(L>>5). P=exp2(S^T) packs with pkrtz in
// natural reg order into the PV B-frag PROVIDED V^T is stored with key-index
// bits 2<->3 swapped (consistent k-slot permutation of A and B). qf=0 on
// half1 kills the k=8..15 padding. Ones-row d=8 of V^T gives the softmax
// denominator; out rows 9..31 are garbage (clamped VT row 9) never stored.
// Plain-exp softmax exact: |score*log2e/sqrt8| <= 4.1 (features <= 1).
// ---------------------------------------------------------------------------
__launch_bounds__(256, 4)
__global__ void attn_kernel(const float* __restrict__ x,
                            const float* __restrict__ theta,
                            _Float16* __restrict__ Ah /* [B*S][128] f16 */) {
  __shared__ __align__(16) _Float16 Kl[CHUNK * 8];   // 8 KB: [key][8 dims]
  __shared__ __align__(16) _Float16 VT[10][VTP];     // 10.2 KB: d 0-7, 8=ones, 9=junk

  const int tid = threadIdx.x;
  const int L   = tid & 63;
  const int ln  = L & 31;
  const int hf  = L >> 5;           // lane half
  const int wv  = tid >> 6;         // wave 0..3
  const int bh     = blockIdx.x >> 4;
  const int qchunk = blockIdx.x & 15;
  const int qb     = qchunk * 128 + wv * 32;   // wave's 32 q rows
  const int b = bh >> 4;
  const int h = bh & 15;

  float th[DK];
#pragma unroll
  for (int i = 0; i < DK; ++i) th[i] = theta[i];

  // VT row 8 = ones (denominator; persists across restages), row 9 = 0
  for (int i = tid; i < VTP; i += 256) {
    VT[8][i] = (_Float16)1.0f;
    VT[9][i] = (_Float16)0.0f;
  }

  const int c0 = qchunk >> 2;       // 512-chunk containing this block's q rows
  const int mrow = (ln < 9) ? ln : 9;   // clamped VT row for PV A-frag
  const float* xb = x + (size_t)b * SEQ * EMB + h * DK;

  float4 pa0, pa1, pb0, pb1;        // prefetched x rows (keys tid, tid+256)
  {
    const float* xp = xb + (size_t)(c0 * CHUNK + tid) * EMB;
    pa0 = *(const float4*)(xp);
    pa1 = *(const float4*)(xp + 4);
    pb0 = *(const float4*)(xp + 256 * EMB);
    pb1 = *(const float4*)(xp + 256 * EMB + 4);
  }

  v8h qf = {0, 0, 0, 0, 0, 0, 0, 0};
  v16f acc;
#pragma unroll
  for (int i = 0; i < 16; ++i) acc[i] = 0.f;
  v16f zf;
#pragma unroll
  for (int i = 0; i < 16; ++i) zf[i] = 0.f;

  for (int cc = 0; cc < NCH; ++cc) {
    if (cc) __syncthreads();

    // ---- stage: features for keys tid, tid+256 (16 B/lane Kl writes) ----
    {
      float r0[8], r1[8];
      r0[0] = __cosf(pa0.x + th[0]);
      r0[1] = r0[0] * __cosf(pa0.y + th[1]);
      r0[2] = r0[1] * __cosf(pa0.z + th[2]);
      r0[3] = r0[2] * __cosf(pa0.w + th[3]);
      r0[4] = r0[3] * __cosf(pa1.x + th[4]);
      r0[5] = r0[4] * __cosf(pa1.y + th[5]);
      r0[6] = r0[5] * __cosf(pa1.z + th[6]);
      r0[7] = r0[6] * __cosf(pa1.w + th[7]);
      r1[0] = __cosf(pb0.x + th[0]);
      r1[1] = r1[0] * __cosf(pb0.y + th[1]);
      r1[2] = r1[1] * __cosf(pb0.z + th[2]);
      r1[3] = r1[2] * __cosf(pb0.w + th[3]);
      r1[4] = r1[3] * __cosf(pb1.x + th[4]);
      r1[5] = r1[4] * __cosf(pb1.y + th[5]);
      r1[6] = r1[5] * __cosf(pb1.z + th[6]);
      r1[7] = r1[6] * __cosf(pb1.w + th[7]);

      _Float16 h0[8], h1[8];
#pragma unroll
      for (int i = 0; i < 8; ++i) { h0[i] = (_Float16)r0[i]; h1[i] = (_Float16)r1[i]; }

      union { v4h v[2]; float4 f; } u0, u1;
      u0.v[0] = (v4h){h0[0], h0[1], h0[2], h0[3]};
      u0.v[1] = (v4h){h0[4], h0[5], h0[6], h0[7]};
      u1.v[0] = (v4h){h1[0], h1[1], h1[2], h1[3]};
      u1.v[1] = (v4h){h1[4], h1[5], h1[6], h1[7]};
      *(float4*)&Kl[tid * 8]         = u0.f;
      *(float4*)&Kl[(tid + 256) * 8] = u1.f;

      // VT with within-16 slot perm (swap bits 2<->3 of key index)
      const int j0 = tid, j1 = tid + 256;
      const int col0 = (j0 & ~15) | (j0 & 3) | ((j0 & 4) << 1) | ((j0 & 8) >> 1);
      const int col1 = (j1 & ~15) | (j1 & 3) | ((j1 & 4) << 1) | ((j1 & 8) >> 1);
#pragma unroll
      for (int d = 0; d < 8; ++d) {
        VT[d][col0] = h0[d];
        VT[d][col1] = h1[d];
      }
    }
    __syncthreads();

    // prefetch next chunk's x rows (consumed after the compute phase)
    if (cc + 1 < NCH) {
      const int cn = (c0 + cc + 1) & (NCH - 1);
      const float* xp = xb + (size_t)(cn * CHUNK + tid) * EMB;
      pa0 = *(const float4*)(xp);
      pa1 = *(const float4*)(xp + 4);
      pb0 = *(const float4*)(xp + 256 * EMB);
      pb1 = *(const float4*)(xp + 256 * EMB + 4);
    }

    // qf from Kl on the q-containing chunk (visited first); half1 stays 0
    if (cc == 0 && hf == 0) {
      const int ql = (qchunk & 3) * 128 + wv * 32 + ln;
      v8h qv = *(const v8h*)&Kl[ql * 8];
      const _Float16 qs = (_Float16)QSCALE;
      const v8h qsc = {qs, qs, qs, qs, qs, qs, qs, qs};
      qf = qv * qsc;
    }

    // ---- compute: 16 32-key blocks, software-pipelined ----
    v8h kf_next = *(const v8h*)&Kl[ln * 8];   // kb = 0
#pragma unroll 2
    for (int kb = 0; kb < CHUNK / 32; ++kb) {
      const v8h kf = kf_next;
      // issue the S-mfma first, then prefetch next kf + this kb's vt while
      // the mfma and exps run
      const v16f s = __builtin_amdgcn_mfma_f32_32x32x16_f16(kf, qf, zf, 0, 0, 0);
      if (kb + 1 < CHUNK / 32)
        kf_next = *(const v8h*)&Kl[((kb + 1) * 32 + ln) * 8];
      const v8h vt0 = *(const v8h*)&VT[mrow][kb * 32 + hf * 8];
      const v8h vt1 = *(const v8h*)&VT[mrow][kb * 32 + 16 + hf * 8];
      union { v2fp p[4]; v8h v; } p0, p1;
#pragma unroll
      for (int i = 0; i < 4; ++i) {
        p0.p[i] = __builtin_amdgcn_cvt_pkrtz(
            __builtin_amdgcn_exp2f(s[2 * i]),
            __builtin_amdgcn_exp2f(s[2 * i + 1]));
        p1.p[i] = __builtin_amdgcn_cvt_pkrtz(
            __builtin_amdgcn_exp2f(s[8 + 2 * i]),
            __builtin_amdgcn_exp2f(s[8 + 2 * i + 1]));
      }
      acc = __builtin_amdgcn_mfma_f32_32x32x16_f16(vt0, p0.v, acc, 0, 0, 0);
      acc = __builtin_amdgcn_mfma_f32_32x32x16_f16(vt1, p1.v, acc, 0, 0, 0);
    }
  }

  // ---- epilogue ----
  // acc C-layout: col=q=L&31, row=(reg&3)+8(reg>>2)+4*hf.
  // half0 regs 0-3 = dims 0-3, reg4 = row 8 = den; half1 regs 0-3 = dims 4-7.
  {
    const float den = __shfl(acc[4], ln, 64);   // from half0 lane ln
    const float inv = 1.0f / den;
    const int qrow = qb + ln;
    v4h o = {(_Float16)(acc[0] * inv), (_Float16)(acc[1] * inv),
             (_Float16)(acc[2] * inv), (_Float16)(acc[3] * inv)};
    *(v4h*)(Ah + ((size_t)b * SEQ + qrow) * EMB + h * DK + hf * 4) = o;
  }
}

// ---------------------------------------------------------------------------
// MFMA projection (unchanged from R10-R15). out = Ah · W^T, fp32 out.
// W converted f32->f16 during LDS staging; W row-major IS the B-fragment
// source. Block: 64 rows x 64 cols (grid 128x2), LDS 35 KB, 4 blocks/CU.
// ---------------------------------------------------------------------------
__launch_bounds__(256, 4)
__global__ void proj_kernel(const _Float16* __restrict__ Ah,
                            const float* __restrict__ W,
                            float* __restrict__ out) {
  __shared__ __align__(16) _Float16 Ahs[64][136];
  __shared__ __align__(16) _Float16 Whs[64][136];

  const int tid  = threadIdx.x;
  const int L    = tid & 63;
  const int wv   = tid >> 6;
  const int quad = L >> 4;
  const int ln   = L & 15;
  const int rowbase = blockIdx.x * 64;
  const int colbase = blockIdx.y * 64;

#pragma unroll
  for (int it = 0; it < 4; ++it) {
    const int idx = it * 256 + tid;
    const int r  = idx >> 4;
    const int c8 = idx & 15;
    *(uint4*)&Ahs[r][c8 * 8] =
        *(const uint4*)(Ah + (size_t)(rowbase + r) * EMB + c8 * 8);
  }
#pragma unroll
  for (int it = 0; it < 8; ++it) {
    const int idx = it * 256 + tid;
    const int n  = idx >> 5;
    const int c4 = idx & 31;
    const float4 w = *(const float4*)(W + (size_t)(colbase + n) * EMB + c4 * 4);
    v4h wh = {(_Float16)w.x, (_Float16)w.y, (_Float16)w.z, (_Float16)w.w};
    *(v4h*)&Whs[n][c4 * 4] = wh;
  }
  __syncthreads();

  v4f acc[4];
#pragma unroll
  for (int nt = 0; nt < 4; ++nt) acc[nt] = (v4f){0.f, 0.f, 0.f, 0.f};

#pragma unroll
  for (int k8 = 0; k8 < 8; ++k8) {
    const v4h af = *(const v4h*)&Ahs[wv * 16 + ln][k8 * 16 + quad * 4];
#pragma unroll
    for (int nt = 0; nt < 4; ++nt) {
      const v4h bf = *(const v4h*)&Whs[nt * 16 + ln][k8 * 16 + quad * 4];
      acc[nt] = __builtin_amdgcn_mfma_f32_16x16x16f16(af, bf, acc[nt], 0, 0, 0);
    }
  }

#pragma unroll
  for (int nt = 0; nt < 4; ++nt) {
    const int col = colbase + nt * 16 + ln;
#pragma unroll
    for (int r = 0; r < 4; ++r) {
      out[(size_t)(rowbase + wv * 16 + quad * 4 + r) * EMB + col] = acc[nt][r];
    }
  }
}

// ---------------------------------------------------------------------------
extern "C" void kernel_launch(void* const* d_in, const int* in_sizes, int n_in,
                              void* d_out, int out_size, void* d_ws, size_t ws_size,
                              hipStream_t stream) {
  const float* x     = (const float*)d_in[0];  // [4,2048,128]
  const float* theta = (const float*)d_in[1];  // [8]
  const float* w_out = (const float*)d_in[2];  // [128,128]
  float* out = (float*)d_out;                  // [4,2048,128]

  _Float16* Ah = (_Float16*)d_ws;              // [8192][128] f16 = 2 MB

  // fused features + attention: 64 bh x 16 q-chunks = 1024 blocks, 4 waves
  attn_kernel<<<dim3(1024), dim3(256), 0, stream>>>(x, theta, Ah);

  // projection: 128 row-tiles x 2 col-tiles
  proj_kernel<<<dim3((BATCH * SEQ) / 64, 2), dim3(256), 0, stream>>>(Ah, w_out, out);
}